// Round 15
// baseline (2483.771 us; speedup 1.0000x reference)
//
#include <hip/hip_runtime.h>
#include <hip/hip_bf16.h>
#include <stdint.h>
#include <stddef.h>

#define TPAD 320   // padded time stride (300 real + 20 pad)
#define TREAL 300

// Python-f64 pool weight: float(1.1*10.0)  (validated exact, rounds 7-14)
#define POOL_W   11.000000000000002

static __device__ __forceinline__ float bf2f(uint16_t b) {
    return __uint_as_float(((uint32_t)b) << 16);
}

// ---------------------------------------------------------------------------
// f64 truncated-alpha IIR + refractory scan (validated exact, rounds 8-14).
// ---------------------------------------------------------------------------
struct IIRC { double DD, C1, C2, C3, DR; };
static __device__ __forceinline__ IIRC iirc_make() {
    IIRC c;
    c.DD = exp(-0.1);
    c.C1 = exp(1.0) / 10.0;
    c.C2 = exp(-9.0) / 10.0;
    c.C3 = 10.0 * exp(-9.0);
    c.DR = exp(-1.0);
    return c;
}
struct IIRS { double P, Q, P2, Q2, r; };
static __device__ __forceinline__ void iirs_init(IIRS& s) {
    s.P = 0.0; s.Q = 0.0; s.P2 = 0.0; s.Q2 = 0.0; s.r = 0.0;
}
static __device__ __forceinline__ bool iir_step(const IIRC& c, IIRS& st,
                                                double x, double xd) {
    double Qn  = c.DD * (st.Q + st.P);
    double Pn  = fma(c.DD, st.P, x);
    double Q2n = c.DD * (st.Q2 + st.P2);
    double P2n = fma(c.DD, st.P2, xd);
    double a = c.C1 * Qn - c.C2 * Q2n - c.C3 * P2n;
    double u = a + st.r;
    bool s = (u >= 10.0);
    st.r = c.DR * (st.r - (s ? 20.0 : 0.0));
    st.P = Pn; st.Q = Qn; st.P2 = P2n; st.Q2 = Q2n;
    return s;
}

// ---------------------------------------------------------------------------
__global__ void detect_kernel(const uint16_t* __restrict__ w1raw, int* __restrict__ flag)
{
    if (threadIdx.x == 0 && blockIdx.x == 0) {
        int sane = 1;
        for (int i = 0; i < 800; ++i) {
            int e = (w1raw[i] >> 7) & 0xFF;
            if (e >= 131) { sane = 0; break; }
        }
        *flag = sane;   // 1 = bf16, 0 = f32
    }
}

// Conv weights -> f64, transposed to [co/COB][tap][COB co-in-group].
__global__ __launch_bounds__(256) void wtrans_kernel(
    const void* __restrict__ w, double* __restrict__ out, int Co, int CKK, int COB,
    const int* __restrict__ flag)
{
    int i = blockIdx.x * 256 + threadIdx.x;
    if (i >= Co * CKK) return;
    int co = i / CKK, r = i - co * CKK;
    double v = (*flag) ? (double)bf2f(((const uint16_t*)w)[i])
                       : (double)((const float*)w)[i];
    out[(size_t)(co / COB) * CKK * COB + (size_t)r * COB + (co % COB)] = v;
}

// Dense weights -> f32 (bf16->f32 exact)
__global__ __launch_bounds__(256) void wcvt_kernel(
    const void* __restrict__ w, float* __restrict__ out, int n, const int* __restrict__ flag)
{
    int i = blockIdx.x * 256 + threadIdx.x;
    if (i >= n) return;
    out[i] = (*flag) ? bf2f(((const uint16_t*)w)[i]) : ((const float*)w)[i];
}

__global__ __launch_bounds__(320) void convert_kernel(
    const void* __restrict__ s_in, uint8_t* __restrict__ u8, const int* __restrict__ flag)
{
    int row = blockIdx.x;
    int t = threadIdx.x;
    uint8_t v = 0;
    if (t < TREAL) {
        float x = (*flag) ? bf2f(((const uint16_t*)s_in)[(size_t)row * TREAL + t])
                          : ((const float*)s_in)[(size_t)row * TREAL + t];
        v = (x >= 0.5f) ? 1 : 0;
    }
    u8[(size_t)row * TPAD + t] = v;
}

// ---------------------------------------------------------------------------
// Conv -> z (f64).  Generic (COB co x PX pixels) per block: one s_load of a
// tap's COB weights feeds COB*PX FMAs.  Round-14 (COB=16,PX=2) L3 chunks ran
// at 21% of the f64 FMA floor (block FMA density too low); COB=32 doubles it.
// Tap order per accumulator identical to r13/r14 -> bitwise-identical z.
// Grid: (Ho*Wo/PX, Co_total/COB, Bg)
// ---------------------------------------------------------------------------
template<int Ci, int CIB, int K, int Hi, int COB, int PX>
__global__ __launch_bounds__(320) void conv_z_kernel(
    const uint8_t* __restrict__ sprev,   // chunk-local [Bg][Ci][Hi][Wi][TPAD]
    const double* __restrict__ Wt,       // [Co/COB][CKK][COB] f64 (exact bf16)
    double* __restrict__ z,              // chunk-local [Bg][Co][Ho][Wo][TPAD]
    int Co_total)
{
    constexpr int P = 1;
    constexpr int Wi = Hi;
    constexpr int Ho = Hi + 2 * P - K + 1;
    constexpr int Wo = Ho;
    constexpr int KK = K * K;
    constexpr int CKK = Ci * KK;
    constexpr int CW = K + PX - 1;        // staged columns
    constexpr int NROW = CIB * K * CW;    // staged 320-B rows per pass
    constexpr int NPASS = Ci / CIB;
    static_assert(Ci % CIB == 0, "pass split");
    static_assert(Wo % PX == 0, "px split");
    static_assert(NROW * 320 <= 60 * 1024, "LDS over limit");
    static_assert(COB * PX <= 64, "acc budget");

    __shared__ uint32_t stage[NROW * 80];

    const int t   = threadIdx.x;             // 0..319
    const int h   = (int)blockIdx.x / (Wo / PX);
    const int w   = ((int)blockIdx.x % (Wo / PX)) * PX;
    const int gy  = (int)blockIdx.y;
    const int co0 = gy * COB;
    const int b   = (int)blockIdx.z;

    double acc[COB][PX];
    #pragma unroll
    for (int c = 0; c < COB; ++c)
        #pragma unroll
        for (int px = 0; px < PX; ++px) acc[c][px] = 0.0;

    const size_t in_b = (size_t)b * Ci * Hi * Wi * TPAD;
    const double* wg = Wt + (size_t)gy * CKK * COB;

    for (int p = 0; p < NPASS; ++p) {
        const int ci0 = p * CIB;
        __syncthreads();
        for (int idx = t; idx < NROW * 80; idx += 320) {
            int r  = idx / 80, dw = idx - (idx / 80) * 80;
            int cl = r / (K * CW);
            int rem = r - cl * (K * CW);
            int ky = rem / CW, cx = rem - ky * CW;
            int row = h - P + ky;
            int col = w - P + cx;
            uint32_t v = 0;
            if ((unsigned)row < (unsigned)Hi && (unsigned)col < (unsigned)Wi)
                v = *(const uint32_t*)(sprev + in_b +
                      (((size_t)(ci0 + cl) * Hi + row) * Wi + col) * TPAD + dw * 4);
            stage[(size_t)r * 80 + dw] = v;
        }
        __syncthreads();

        const uint8_t* sbytes = (const uint8_t*)stage;
        #pragma unroll 1
        for (int cl = 0; cl < CIB; ++cl) {
            #pragma unroll
            for (int ky = 0; ky < K; ++ky) {
                #pragma unroll
                for (int kx = 0; kx < K; ++kx) {
                    const int rbase = ((cl * K + ky) * CW + kx) * 320;
                    double x[PX];
                    #pragma unroll
                    for (int px = 0; px < PX; ++px)
                        x[px] = (double)sbytes[rbase + 320 * px + t];
                    const double* wrow = wg +
                        ((size_t)((ci0 + cl) * KK + ky * K + kx)) * COB;  // uniform -> s_load
                    #pragma unroll
                    for (int c = 0; c < COB; ++c) {
                        double wv = wrow[c];
                        #pragma unroll
                        for (int px = 0; px < PX; ++px)
                            acc[c][px] = fma(wv, x[px], acc[c][px]);
                    }
                }
            }
        }
    }

    #pragma unroll
    for (int c = 0; c < COB; ++c) {
        #pragma unroll
        for (int px = 0; px < PX; ++px) {
            size_t row = (((size_t)b * Co_total + co0 + c) * Ho + h) * Wo + w + px;
            z[row * TPAD + t] = acc[c][px];
        }
    }
}

// ---------------------------------------------------------------------------
// PSP + scan over z (validated r13/r14): lane = row, bits-in-registers ->
// LDS transpose -> coalesced u32 stores.
// ---------------------------------------------------------------------------
__global__ __launch_bounds__(256) void psp_scan_kernel(
    const double* __restrict__ z, uint8_t* __restrict__ sout, int N)
{
    __shared__ uint32_t bits[256 * 11];
    const int tid = threadIdx.x;
    const int n0 = blockIdx.x * 256;
    const int n = n0 + tid;
    const bool active = (n < N);

    if (active) {
        const double* zr = z + (size_t)n * TPAD;
        const IIRC c = iirc_make();
        IIRS st; iirs_init(st);
        uint32_t bw = 0;
        #pragma unroll 5
        for (int t0 = 0; t0 < 100; t0 += 4) {
            double2 xa = *(const double2*)(zr + t0);
            double2 xb = *(const double2*)(zr + t0 + 2);
            if (iir_step(c, st, xa.x, 0.0)) bw |= 1u << (t0 & 31);
            if (iir_step(c, st, xa.y, 0.0)) bw |= 1u << ((t0 + 1) & 31);
            if (iir_step(c, st, xb.x, 0.0)) bw |= 1u << ((t0 + 2) & 31);
            if (iir_step(c, st, xb.y, 0.0)) bw |= 1u << ((t0 + 3) & 31);
            if ((t0 & 31) == 28) { bits[tid * 11 + (t0 >> 5)] = bw; bw = 0; }
        }
        #pragma unroll 5
        for (int t0 = 100; t0 < TREAL; t0 += 4) {
            double2 xa = *(const double2*)(zr + t0);
            double2 xb = *(const double2*)(zr + t0 + 2);
            double2 da = *(const double2*)(zr + t0 - 100);
            double2 db = *(const double2*)(zr + t0 - 98);
            if (iir_step(c, st, xa.x, da.x)) bw |= 1u << (t0 & 31);
            if (iir_step(c, st, xa.y, da.y)) bw |= 1u << ((t0 + 1) & 31);
            if (iir_step(c, st, xb.x, db.x)) bw |= 1u << ((t0 + 2) & 31);
            if (iir_step(c, st, xb.y, db.y)) bw |= 1u << ((t0 + 3) & 31);
            if ((t0 & 31) == 28) { bits[tid * 11 + (t0 >> 5)] = bw; bw = 0; }
        }
        bits[tid * 11 + 9] = bw;
    }
    __syncthreads();

    for (int task = tid; task < 256 * 80; task += 256) {
        int nl = task / 80, w = task - nl * 80;
        int ng = n0 + nl;
        if (ng >= N) continue;
        int tb = w * 4;
        uint32_t word = bits[nl * 11 + (tb >> 5)];
        uint32_t o = 0;
        #pragma unroll
        for (int j = 0; j < 4; ++j)
            if ((word >> ((tb + j) & 31)) & 1u) o |= 1u << (8 * j);
        *(uint32_t*)(sout + (size_t)ng * TPAD + tb) = o;
    }
}

// ---------------------------------------------------------------------------
// Pool + PSP + scan v2 (validated r13/r14): LDS cnt tile, coalesced in/out.
// ---------------------------------------------------------------------------
template<int C, int Hi>
__global__ __launch_bounds__(256) void pool_psp_v2_kernel(
    const uint8_t* __restrict__ sprev, uint8_t* __restrict__ sout, int N)
{
    constexpr int Wi = Hi, Ho = Hi / 2, Wo = Wi / 2;
    __shared__ uint32_t cnt[128 * 81];
    __shared__ uint32_t bits[128 * 11];
    const int tid = threadIdx.x;
    const int n0 = blockIdx.x * 128;

    for (int task = tid; task < 128 * 80; task += 256) {
        int nl = task / 80, w = task - nl * 80;
        int n = n0 + nl;
        if (n >= N) continue;
        int wo = n % Wo;  int r1 = n / Wo;
        int ho = r1 % Ho; int r2 = r1 / Ho;
        int cc = r2 % C;  int b  = r2 / C;
        const uint8_t* p0 = sprev +
            ((((size_t)b * C + cc) * Hi + 2 * ho) * Wi + 2 * wo) * TPAD + w * 4;
        uint32_t a0 = *(const uint32_t*)p0;
        uint32_t a1 = *(const uint32_t*)(p0 + TPAD);
        uint32_t a2 = *(const uint32_t*)(p0 + (size_t)Wi * TPAD);
        uint32_t a3 = *(const uint32_t*)(p0 + (size_t)(Wi + 1) * TPAD);
        cnt[nl * 81 + w] = a0 + a1 + a2 + a3;
    }
    __syncthreads();

    if (tid < 128 && n0 + tid < N) {
        const uint8_t* cb = (const uint8_t*)cnt + (size_t)tid * 324;
        const IIRC c = iirc_make();
        IIRS st; iirs_init(st);
        uint32_t bw = 0;
        for (int t = 0; t < 100; ++t) {
            double x = POOL_W * (double)cb[t];
            if (iir_step(c, st, x, 0.0)) bw |= 1u << (t & 31);
            if ((t & 31) == 31) { bits[tid * 11 + (t >> 5)] = bw; bw = 0; }
        }
        for (int t = 100; t < TREAL; ++t) {
            double x  = POOL_W * (double)cb[t];
            double xd = POOL_W * (double)cb[t - 100];
            if (iir_step(c, st, x, xd)) bw |= 1u << (t & 31);
            if ((t & 31) == 31) { bits[tid * 11 + (t >> 5)] = bw; bw = 0; }
        }
        bits[tid * 11 + 9] = bw;
    }
    __syncthreads();

    for (int task = tid; task < 128 * 80; task += 256) {
        int nl = task / 80, w = task - nl * 80;
        int n = n0 + nl;
        if (n >= N) continue;
        int tb = w * 4;
        uint32_t word = bits[nl * 11 + (tb >> 5)];
        uint32_t o = 0;
        #pragma unroll
        for (int j = 0; j < 4; ++j)
            if ((word >> ((tb + j) & 31)) & 1u) o |= 1u << (8 * j);
        *(uint32_t*)(sout + (size_t)n * TPAD + tb) = o;
    }
}

// ---------------------------------------------------------------------------
// Dense partials: grid (5, B, 16) (validated r9+).
// ---------------------------------------------------------------------------
__global__ __launch_bounds__(256) void dense_partial_kernel(
    const uint8_t* __restrict__ s5, const float* __restrict__ Wf,
    double* __restrict__ partial)
{
    const int tc = blockIdx.x, b = blockIdx.y, p = blockIdx.z;
    const int tid = threadIdx.x;
    const int tl = tid & 63, slot = tid >> 6;
    const int t = tc * 64 + tl;
    const int i0 = p * 256 + slot * 64;
    double acc[10];
    #pragma unroll
    for (int o = 0; o < 10; ++o) acc[o] = 0.0;
    const uint8_t* sp = s5 + ((size_t)b * 4096 + i0) * TPAD + t;
    for (int i = 0; i < 64; ++i) {
        float f = (float)sp[(size_t)i * TPAD];
        if (__any(f != 0.f)) {
            #pragma unroll
            for (int o = 0; o < 10; ++o)
                acc[o] = fma((double)Wf[o * 4096 + i0 + i], (double)f, acc[o]);
        }
    }
    __shared__ double red[4][64][10];
    #pragma unroll
    for (int o = 0; o < 10; ++o) red[slot][tl][o] = acc[o];
    __syncthreads();
    if (slot == 0) {
        #pragma unroll
        for (int o = 0; o < 10; ++o) {
            double v = ((red[0][tl][o] + red[1][tl][o]) + red[2][tl][o]) + red[3][tl][o];
            partial[((size_t)p * 160 + (size_t)b * 10 + o) * TPAD + t] = v;
        }
    }
}

// ---------------------------------------------------------------------------
// Final: one launch, block per (b,o) row (validated rounds 9-14).
// ---------------------------------------------------------------------------
__global__ __launch_bounds__(320) void psp_out_final_kernel(
    const double* __restrict__ partial, void* __restrict__ out,
    const int* __restrict__ flag)
{
    __shared__ double xs[TPAD];
    __shared__ uint8_t sb[TREAL];
    const int n = blockIdx.x;
    const int t = threadIdx.x;
    double v = 0.0;
    #pragma unroll
    for (int p = 0; p < 16; ++p)
        v += partial[((size_t)p * 160 + n) * TPAD + t];
    xs[t] = v;
    __syncthreads();
    if (t == 0) {
        const IIRC c = iirc_make();
        IIRS st; iirs_init(st);
        for (int i = 0; i < TREAL; ++i) {
            double xd = (i >= 100) ? xs[i - 100] : 0.0;
            sb[i] = iir_step(c, st, xs[i], xd) ? 1 : 0;
        }
    }
    __syncthreads();
    if (t < TREAL) {
        size_t e = (size_t)n * TREAL + t;
        if (*flag) ((uint16_t*)out)[e] = sb[t] ? 0x3F80 : 0;
        else       ((float*)out)[e]    = sb[t] ? 1.0f : 0.0f;
    }
}

// ---------------------------------------------------------------------------
__global__ __launch_bounds__(256) void fill_kernel(float* __restrict__ out, int n, float v)
{
    int i = blockIdx.x * 256 + threadIdx.x;
    if (i < n) out[i] = v;
}

// ---------------------------------------------------------------------------
static inline size_t alignup(size_t x) { return (x + 255) & ~(size_t)255; }
static inline int pick_bg(size_t per_b, size_t budget) {
    const int cand[5] = {16, 8, 4, 2, 1};
    for (int k = 0; k < 5; ++k)
        if (per_b * (size_t)cand[k] <= budget) return cand[k];
    return 0;
}

extern "C" void kernel_launch(void* const* d_in, const int* in_sizes, int n_in,
                              void* d_out, int out_size, void* d_ws, size_t ws_size,
                              hipStream_t stream)
{
    if (n_in != 5 || in_sizes[0] != 16 * 2 * 34 * 34 * 300 || in_sizes[1] != 800 ||
        in_sizes[2] != 4608 || in_sizes[3] != 18432 || in_sizes[4] != 40960 ||
        out_size != 16 * 10 * 300) {
        fill_kernel<<<(out_size + 255) / 256, 256, 0, stream>>>((float*)d_out, out_size, 2.0e5f);
        return;
    }

    const size_t flag_sz  = alignup(sizeof(int));
    const size_t w64_sz   = alignup((size_t)(800 + 4608 + 18432) * 8);
    const size_t wf32_sz  = alignup((size_t)40960 * 4);
    const size_t sin8_sz  = alignup((size_t)16 * 2 * 34 * 34 * TPAD);
    const size_t dpart_sz = alignup((size_t)16 * 160 * TPAD * 8);
    const size_t sA_sz    = alignup((size_t)16 * 16384 * TPAD);
    const size_t sB_sz    = alignup((size_t)16 * 4096 * TPAD);
    const size_t base_sz  = flag_sz + w64_sz + wf32_sz + sin8_sz + dpart_sz + sA_sz + sB_sz;
    if (base_sz + 256 > ws_size) {
        fill_kernel<<<(out_size + 255) / 256, 256, 0, stream>>>((float*)d_out, out_size, 1.0e5f);
        return;
    }
    const size_t zbud = ws_size - base_sz - 256;

    const size_t zb1 = (size_t)16 * 1024 * TPAD * 8;
    const size_t zb3 = (size_t)32 * 256 * TPAD * 8;
    const size_t zb5 = (size_t)64 * 64 * TPAD * 8;
    const int bg1 = pick_bg(zb1, zbud), bg3 = pick_bg(zb3, zbud), bg5 = pick_bg(zb5, zbud);
    if (bg1 == 0 || bg3 == 0 || bg5 == 0) {
        fill_kernel<<<(out_size + 255) / 256, 256, 0, stream>>>((float*)d_out, out_size, 1.0e5f);
        return;
    }

    char* base = (char*)d_ws;
    int* flag = (int*)base;          base += flag_sz;
    double* w64 = (double*)base;     base += w64_sz;
    float* wf32 = (float*)base;      base += wf32_sz;
    uint8_t* sin8 = (uint8_t*)base;  base += sin8_sz;
    double* dpart = (double*)base;   base += dpart_sz;
    uint8_t* sA = (uint8_t*)base;    base += sA_sz;
    uint8_t* sB = (uint8_t*)base;    base += sB_sz;
    double* z64 = (double*)base;

    detect_kernel<<<1, 64, 0, stream>>>((const uint16_t*)d_in[1], flag);

    double* Wt1 = w64;                 // [1][50][16]
    double* Wt2 = w64 + 800;           // [1][144][32]
    double* Wt3 = w64 + 800 + 4608;    // [2][288][32]
    wtrans_kernel<<<(800 + 255) / 256, 256, 0, stream>>>(d_in[1], Wt1, 16, 50, 16, flag);
    wtrans_kernel<<<(4608 + 255) / 256, 256, 0, stream>>>(d_in[2], Wt2, 32, 144, 32, flag);
    wtrans_kernel<<<(18432 + 255) / 256, 256, 0, stream>>>(d_in[3], Wt3, 64, 288, 32, flag);
    wcvt_kernel<<<(40960 + 255) / 256, 256, 0, stream>>>(d_in[4], wf32, 40960, flag);
    convert_kernel<<<16 * 2 * 34 * 34, 320, 0, stream>>>(d_in[0], sin8, flag);

    // L1: conv 2->16, 5x5 pad1, 34->32 (COB=16, PX=4; stage 25.6 KB, 1 pass)
    for (int b0 = 0; b0 < 16; b0 += bg1) {
        conv_z_kernel<2, 2, 5, 34, 16, 4><<<dim3(32 * 8, 1, bg1), 320, 0, stream>>>(
            sin8 + (size_t)b0 * 2 * 34 * 34 * TPAD, Wt1, z64, 16);
        int N = bg1 * 16384;
        psp_scan_kernel<<<(N + 255) / 256, 256, 0, stream>>>(
            z64, sA + (size_t)b0 * 16384 * TPAD, N);
    }
    // L2: pool 32->16, coalesced v2
    pool_psp_v2_kernel<16, 32><<<(16 * 4096 + 127) / 128, 256, 0, stream>>>(
        sA, sB, 16 * 4096);
    // L3: conv 16->32, 3x3 pad1, 16->16 (COB=32, PX=2; CIB=8, 2 passes)
    for (int b0 = 0; b0 < 16; b0 += bg3) {
        conv_z_kernel<16, 8, 3, 16, 32, 2><<<dim3(16 * 8, 1, bg3), 320, 0, stream>>>(
            sB + (size_t)b0 * 16 * 256 * TPAD, Wt2, z64, 32);
        int N = bg3 * 8192;
        psp_scan_kernel<<<(N + 255) / 256, 256, 0, stream>>>(
            z64, sA + (size_t)b0 * 8192 * TPAD, N);
    }
    // L4: pool 16->8, coalesced v2
    pool_psp_v2_kernel<32, 16><<<(16 * 2048 + 127) / 128, 256, 0, stream>>>(
        sA, sB, 16 * 2048);
    // L5: conv 32->64, 3x3 pad1, 8->8 (COB=32, PX=2; CIB=8, 4 passes)
    for (int b0 = 0; b0 < 16; b0 += bg5) {
        conv_z_kernel<32, 8, 3, 8, 32, 2><<<dim3(8 * 4, 2, bg5), 320, 0, stream>>>(
            sB + (size_t)b0 * 32 * 64 * TPAD, Wt3, z64, 64);
        int N = bg5 * 4096;
        psp_scan_kernel<<<(N + 255) / 256, 256, 0, stream>>>(
            z64, sA + (size_t)b0 * 4096 * TPAD, N);
    }
    // L6: dense partials + single final scan
    dense_partial_kernel<<<dim3(5, 16, 16), 256, 0, stream>>>(sA, wf32, dpart);
    psp_out_final_kernel<<<160, 320, 0, stream>>>(dpart, d_out, flag);
}